// Round 1
// baseline (569.322 us; speedup 1.0000x reference)
//
#include <hip/hip_runtime.h>

// Problem constants (fixed by setup_inputs): B=2, N=2048, F=16, f=8, stride=4
// starts: 0,4,...,2040 -> 511 windows; 56 off-diagonal offsets per window.
// out shape (B, 511, 56*16=896) fp32.

constexpr int B_      = 2;
constexpr int N_      = 2048;
constexpr int F_      = 16;
constexpr int STRIDE_ = 4;
constexpr int NS_     = 511;   // number of window starts
constexpr int K_      = 56;    // off-diagonal offsets per window
constexpr int V_      = F_ / 4; // float4 per gathered segment

// One thread per float4 of output. total = B*NS*K*V = 228,928 threads.
// k -> (ii,jj): local = (k/8)*9 + 1 + (k%8); ii = local/8; jj = local%8.
// Within a k-group of 8, source segments are contiguous (512B runs) ->
// 32 consecutive lanes read 512 contiguous bytes. Writes fully contiguous.
__global__ void unfold_offdiag_kernel(const float* __restrict__ adj,
                                      float* __restrict__ out) {
    const int total = B_ * NS_ * K_ * V_;
    int t = blockIdx.x * blockDim.x + threadIdx.x;
    if (t >= total) return;

    int f4   = t & 3;          // which float4 within the 16-float segment
    int seg  = t >> 2;         // segment id: (b, s, k)
    int k    = seg % K_;
    int rest = seg / K_;
    int s    = rest % NS_;
    int b    = rest / NS_;

    int g     = k >> 3;        // group index (0..6)
    int p     = k & 7;         // position within group
    int local = g * 9 + 1 + p; // skip diagonal entries local%9==0
    int ii    = local >> 3;
    int jj    = local & 7;

    int row = s * STRIDE_ + ii;
    int col = s * STRIDE_ + jj;

    const float4* src =
        (const float4*)(adj + (((size_t)b * N_ + row) * N_ + col) * F_) + f4;
    float4* dst =
        (float4*)(out + (((size_t)b * NS_ + s) * (K_ * F_) + (size_t)k * F_)) + f4;

    *dst = *src;
}

extern "C" void kernel_launch(void* const* d_in, const int* in_sizes, int n_in,
                              void* d_out, int out_size, void* d_ws, size_t ws_size,
                              hipStream_t stream) {
    const float* adj = (const float*)d_in[0];
    float* out = (float*)d_out;

    const int total  = B_ * NS_ * K_ * V_;   // 228,928
    const int block  = 256;
    const int grid   = (total + block - 1) / block;  // 895

    unfold_offdiag_kernel<<<grid, block, 0, stream>>>(adj, out);
}

// Round 2
// 563.581 us; speedup vs baseline: 1.0102x; 1.0102x over previous
//
#include <hip/hip_runtime.h>

// Problem constants (fixed by setup_inputs): B=2, N=2048, F=16, f=8, stride=4
// starts: 0,4,...,2040 -> 511 windows; 56 off-diagonal offsets per window.
// out shape (B, 511, 56*16=896) fp32.
//
// Key structure: per-batch output is 511*56*4 = 114464 float4s. The two
// batches share identical (s,k,f4) gather math -> one thread copies the same
// (s,k,f4) for b=0 AND b=1: half the grid, index math amortized 2x, and two
// independent load/store pairs per thread for ILP.

constexpr int B_      = 2;
constexpr int N_      = 2048;
constexpr int F_      = 16;
constexpr int STRIDE_ = 4;
constexpr int NS_     = 511;     // number of window starts
constexpr int K_      = 56;      // off-diagonal offsets per window
constexpr int V_      = F_ / 4;  // float4 per gathered segment
constexpr int PER_B_  = NS_ * K_ * V_;          // 114464 float4 per batch
constexpr size_t ADJ_B_STRIDE = (size_t)N_ * N_ * F_;  // floats per batch in adj
constexpr size_t OUT_B_STRIDE = (size_t)NS_ * K_ * F_; // floats per batch in out

__global__ __launch_bounds__(256) void unfold_offdiag_kernel(
    const float* __restrict__ adj, float* __restrict__ out) {
    int t = blockIdx.x * blockDim.x + threadIdx.x;
    if (t >= PER_B_) return;

    int f4  = t & 3;           // which float4 within the 16-float segment
    int seg = t >> 2;          // segment id: (s, k)
    int k   = seg % K_;
    int s   = seg / K_;

    int g     = k >> 3;        // group index (0..6)
    int p     = k & 7;         // position within group
    int local = g * 9 + 1 + p; // skip diagonal entries (local % 9 == 0)
    int ii    = local >> 3;
    int jj    = local & 7;

    int row = s * STRIDE_ + ii;
    int col = s * STRIDE_ + jj;

    size_t src_off = (((size_t)row * N_ + col) * F_) + (size_t)f4 * 4;
    size_t dst_off = ((size_t)s * (K_ * F_) + (size_t)k * F_) + (size_t)f4 * 4;

    const float4* s0 = (const float4*)(adj + src_off);
    const float4* s1 = (const float4*)(adj + ADJ_B_STRIDE + src_off);
    float4 v0 = *s0;           // two independent loads in flight
    float4 v1 = *s1;
    *(float4*)(out + dst_off)                = v0;
    *(float4*)(out + OUT_B_STRIDE + dst_off) = v1;
}

extern "C" void kernel_launch(void* const* d_in, const int* in_sizes, int n_in,
                              void* d_out, int out_size, void* d_ws, size_t ws_size,
                              hipStream_t stream) {
    const float* adj = (const float*)d_in[0];
    float* out = (float*)d_out;

    const int block = 256;
    const int grid  = (PER_B_ + block - 1) / block;  // 448

    unfold_offdiag_kernel<<<grid, block, 0, stream>>>(adj, out);
}